// Round 9
// baseline (19.295 us; speedup 1.0000x reference)
//
#include <hip/hip_runtime.h>
#include <cstddef>

#define POOL 7
#define NEGV (-3e38f)

__device__ __forceinline__ float4 fmax4(float4 a, float4 b) {
    return make_float4(fmaxf(a.x, b.x), fmaxf(a.y, b.y),
                       fmaxf(a.z, b.z), fmaxf(a.w, b.w));
}

// Both of this wave's pooled-row windows in ONE load batch: 2*P independent
// global_load_dwordx4 issued back-to-back (no branch between), one vmcnt
// wait, then both reductions. P = psh >= any window length; clamped re-loads
// of the last valid row are max-idempotent; empty windows killed afterwards.
template<int P>
__device__ __forceinline__ void two_windows(const float4* __restrict__ fp4,
        int ys0, int yc0, bool e0, int ys1, int yc1, bool e1, int xq,
        float4& m0, float4& m1) {
    float4 t0[P], t1[P];
#pragma unroll
    for (int k = 0; k < P; ++k) t0[k] = fp4[(min(ys0 + k, yc0) << 4) + xq];
#pragma unroll
    for (int k = 0; k < P; ++k) t1[k] = fp4[(min(ys1 + k, yc1) << 4) + xq];
    m0 = t0[0];
    m1 = t1[0];
#pragma unroll
    for (int k = 1; k < P; ++k) { m0 = fmax4(m0, t0[k]); m1 = fmax4(m1, t1[k]); }
    const float4 neg = make_float4(NEGV, NEGV, NEGV, NEGV);
    if (e0) m0 = neg;
    if (e1) m1 = neg;
}

// Block = one (ROI, 4-channel group); wave wv owns pooled rows {2wv, 2wv+1}
// (wv=3: row 6, duplicated harmlessly). Exactly one uniform branch (psh
// switch), one vmcnt wait, one lgkm wait per wave. No barriers, no atomics.
__global__ __launch_bounds__(256) void roi_pool_kernel(
    const float* __restrict__ feat, const float4* __restrict__ rois4,
    float* __restrict__ out)
{
    const int tid  = threadIdx.x;
    const int lane = tid & 63;
    const int wv   = tid >> 6;
    const int bid  = blockIdx.x;
    // bid = br*64 + c4: XCD = bid%8 = c4%8 -> each XCD owns a fixed channel
    // slice (2 MB feature working set, L2-resident).
    const int br = bid >> 6;            // b*64 + r
    const int c4 = bid & 63;            // 4-channel group
    const int b  = br >> 6;
    const int cs = lane >> 4;           // channel slot 0..3
    const int lx = lane & 15;           // quad slot 0..15

    // ---- ROI decode; force SGPR so downstream address math scalarizes ----
    const float4 rv = rois4[br];
    const int px = __builtin_amdgcn_readfirstlane(__float2int_rn(rv.x * 0.0625f));
    const int py = __builtin_amdgcn_readfirstlane(__float2int_rn(rv.y * 0.0625f));
    const int qx = __builtin_amdgcn_readfirstlane(__float2int_rn(rv.z * 0.0625f));
    const int qy = __builtin_amdgcn_readfirstlane(__float2int_rn(rv.w * 0.0625f));
    const int roi_w = max(qx - px + 1, 1);
    const int roi_h = max(qy - py + 1, 1);
    const int psw = (roi_w + POOL - 1) / POOL;
    const int psh = (roi_h + POOL - 1) / POOL;
    const int pad_l = (psw * POOL - roi_w) >> 1;
    const int pad_t = (psh * POOL - roi_h) >> 1;

    // quad coverage of [px,qx]; clamped duplicate lanes hit the same lines
    const int qbase = px >> 2;
    const int nq    = (qx >> 2) - qbase + 1;
    const int xq    = qbase + min(lx, nq - 1);

    const int c = (c4 << 2) + cs;
    const float4* fp4 = (const float4*)feat + ((size_t)((b << 8) + c) << 10);

    // this wave's two pooled rows
    const int i0 = wv << 1;
    const int i1 = min(i0 + 1, 6);
    const int lo0 = max(i0 * psh - pad_t, 0);
    const int hi0 = min((i0 + 1) * psh - pad_t, roi_h) - 1;
    const int lo1 = max(i1 * psh - pad_t, 0);
    const int hi1 = min((i1 + 1) * psh - pad_t, roi_h) - 1;
    const int ys0 = py + lo0, yc0 = min(py + max(hi0, lo0), 63);
    const int ys1 = py + lo1, yc1 = min(py + max(hi1, lo1), 63);
    const bool e0 = hi0 < lo0;
    const bool e1 = hi1 < lo1;

    // ---- phase 1: ONE uniform branch, ONE load batch, ONE wait ----
    float4 m0, m1;
    switch (psh) {
        case 1:  two_windows<1 >(fp4, ys0, yc0, e0, ys1, yc1, e1, xq, m0, m1); break;
        case 2:  two_windows<2 >(fp4, ys0, yc0, e0, ys1, yc1, e1, xq, m0, m1); break;
        case 3:  two_windows<3 >(fp4, ys0, yc0, e0, ys1, yc1, e1, xq, m0, m1); break;
        case 4:  two_windows<4 >(fp4, ys0, yc0, e0, ys1, yc1, e1, xq, m0, m1); break;
        case 5:  two_windows<5 >(fp4, ys0, yc0, e0, ys1, yc1, e1, xq, m0, m1); break;
        case 6:  two_windows<6 >(fp4, ys0, yc0, e0, ys1, yc1, e1, xq, m0, m1); break;
        case 7:  two_windows<7 >(fp4, ys0, yc0, e0, ys1, yc1, e1, xq, m0, m1); break;
        case 8:  two_windows<8 >(fp4, ys0, yc0, e0, ys1, yc1, e1, xq, m0, m1); break;
        case 9:  two_windows<9 >(fp4, ys0, yc0, e0, ys1, yc1, e1, xq, m0, m1); break;
        default: two_windows<10>(fp4, ys0, yc0, e0, ys1, yc1, e1, xq, m0, m1); break;
    }

    // ---- LDS handoff, both rows (same wave, in-order DS pipe: no barrier) ----
    __shared__ __attribute__((aligned(16))) float lds[4][2][4][64];
    float* ldsw = &lds[wv][0][0][0];
    const int woff = (xq - qbase) << 2;
    *(float4*)(ldsw + ((0 * 4 + cs) << 6) + woff) = m0;
    *(float4*)(ldsw + ((1 * 4 + cs) << 6) + woff) = m1;

    // ---- phase 2: straight-line clamped reads (width <= psw <= 10), both rows ----
    const bool active = lane < 28;
    const int li  = min(lane, 27);
    const int i7  = li / 7;             // channel slot
    const int j7  = li - i7 * 7;        // pooled column
    const int pxl = px & 3;
    const int lox = max(j7 * psw - pad_l, 0);
    const int hix = min((j7 + 1) * psw - pad_l, roi_w) - 1;
    const int xs  = pxl + lox;
    const int xe  = pxl + hix;          // < xs if empty
    const int xec = max(xe, 0);
    const bool xempty = xe < xs;
    const bool padc = (j7 * psw < pad_l) | ((j7 + 1) * psw > pad_l + roi_w);

    const float* r0 = ldsw + ((0 * 4 + i7) << 6);
    const float* r1 = ldsw + ((1 * 4 + i7) << 6);
    float a0[10], a1[10];
#pragma unroll
    for (int k = 0; k < 10; ++k) {
        const int x = min(xs + k, xec);
        a0[k] = r0[x];
        a1[k] = r1[x];
    }
    float v0 = a0[0], v1 = a1[0];
#pragma unroll
    for (int k = 1; k < 10; ++k) { v0 = fmaxf(v0, a0[k]); v1 = fmaxf(v1, a1[k]); }
    if (xempty | e0) v0 = NEGV;
    if (xempty | e1) v1 = NEGV;
    const bool padr0 = (i0 * psh < pad_t) | ((i0 + 1) * psh > pad_t + roi_h);
    const bool padr1 = (i1 * psh < pad_t) | ((i1 + 1) * psh > pad_t + roi_h);
    if (padr0 | padc) v0 = fmaxf(v0, 0.0f);
    if (padr1 | padc) v1 = fmaxf(v1, 0.0f);

    const size_t obase = ((size_t)(br << 8) + (c4 << 2) + i7) * 49 + j7;
    if (active) {
        out[obase + (size_t)i0 * 7] = v0;
        if (i1 != i0) out[obase + (size_t)i1 * 7] = v1;
    }
}

extern "C" void kernel_launch(void* const* d_in, const int* in_sizes, int n_in,
                              void* d_out, int out_size, void* d_ws, size_t ws_size,
                              hipStream_t stream) {
    const float* feat = (const float*)d_in[0];
    const float* rois = (const float*)d_in[1];
    float* out = (float*)d_out;

    // 128 ROIs x 64 channel-quads; one block per (ROI, 4-channel group)
    const int blocks = 2 * 64 * 64;     // 8192
    roi_pool_kernel<<<blocks, 256, 0, stream>>>(
        feat, (const float4*)rois, out);
}

// Round 10
// 17.212 us; speedup vs baseline: 1.1211x; 1.1211x over previous
//
#include <hip/hip_runtime.h>
#include <cstddef>

#define POOL 7
#define NEGV (-3e38f)

__device__ __forceinline__ float4 fmax4(float4 a, float4 b) {
    return make_float4(fmaxf(a.x, b.x), fmaxf(a.y, b.y),
                       fmaxf(a.z, b.z), fmaxf(a.w, b.w));
}

// Phase 1: per-lane column maxes (1 quad = 4 columns) for the 7 pooled rows.
// Loads batched into statically-indexed register arrays before any fmax ->
// back-to-back global_load_dwordx4, one vmcnt wait per batch. y addresses are
// SGPR-uniform; clamped re-loads of the last valid row are max-idempotent.
template<int KL>
__device__ __forceinline__ void col_max4(const float4* __restrict__ fp4,
        int py, int psh, int pad_t, int roi_h, int xq, float4 (&acc)[POOL]) {
    constexpr int B1 = (KL <= 6) ? KL : (KL + 1) / 2;   // batch size (10->5, 8->4)
    constexpr int NB = (KL + B1 - 1) / B1;
#pragma unroll
    for (int i = 0; i < POOL; ++i) {
        const int lo = max(i * psh - pad_t, 0);
        const int hi = min((i + 1) * psh - pad_t, roi_h) - 1;
        const int ys = py + lo;
        const int yc = min(py + max(hi, lo), 63);       // empty-safe, in-bounds
        float4 m = make_float4(NEGV, NEGV, NEGV, NEGV);
#pragma unroll
        for (int bb = 0; bb < NB; ++bb) {
            float4 t[B1];
#pragma unroll
            for (int k = 0; k < B1; ++k) {
                const int y = min(ys + bb * B1 + k, yc);   // scalar chain
                t[k] = fp4[(y << 4) + xq];
            }
#pragma unroll
            for (int k = 0; k < B1; ++k) m = fmax4(m, t[k]);
        }
        if (lo > hi) m = make_float4(NEGV, NEGV, NEGV, NEGV);
        acc[i] = m;
    }
}

// Phase 2: parity-double-buffered LDS handoff (wave-in-order DS pipe, no
// barriers). Reads batched into registers -> one lgkm wait per pooled row.
template<int KW>
__device__ __forceinline__ void phase2_run(const float4 (&acc)[POOL],
        float* ldsbase, int Lq, int cs, bool active, int i7,
        int xs, int xec, bool xempty, bool padc,
        int psh, int pad_t, int roi_h,
        float* __restrict__ out, size_t obase) {
#pragma unroll
    for (int i = 0; i < POOL; ++i) {
        float* wrow = ldsbase + (((i & 1) << 2) + cs) * 64;
        *(float4*)(wrow + (Lq << 2)) = acc[i];
        if (active) {
            const float* rrow = ldsbase + (((i & 1) << 2) + i7) * 64;
            float t[KW];
#pragma unroll
            for (int k = 0; k < KW; ++k) t[k] = rrow[min(xs + k, xec)];
            float m = t[0];
#pragma unroll
            for (int k = 1; k < KW; ++k) m = fmaxf(m, t[k]);
            if (xempty) m = NEGV;
            const bool padr = (i * psh < pad_t) | ((i + 1) * psh > pad_t + roi_h);
            if (padr | padc) m = fmaxf(m, 0.0f);
            out[obase + (size_t)i * 7] = m;
        }
    }
}

__global__ __launch_bounds__(256) void roi_pool_kernel(
    const float* __restrict__ feat, const float* __restrict__ rois,
    float* __restrict__ out)
{
    const int tid  = threadIdx.x;
    const int lane = tid & 63;
    const int wv   = tid >> 6;
    const int bid  = blockIdx.x;

    // XCD-aware decode: blocks with bid%8 == x (round-robin onto XCD x) own a
    // fixed 32-channel slice -> per-XCD feature working set = 1 MB (L2-fits).
    // Bijective: bid = (br<<4) | (cglo<<3) | (cg>>1), cg = ((bid&7)<<1)|cglo.
    const int br = bid >> 4;                                // b*64 + r
    const int cg = ((bid & 7) << 1) | ((bid >> 3) & 1);     // channel group 0..15
    const int b  = br >> 6;
    const int c0 = (cg << 4) + (wv << 2);                   // wave's first channel
    const int cs = lane >> 4;                               // channel slot 0..3
    const int lx = lane & 15;                               // quad slot 0..15

    // ---- ROI decode; force SGPR so downstream address math scalarizes ----
    const float* rp = rois + (size_t)br * 4;
    const int px = __builtin_amdgcn_readfirstlane(__float2int_rn(rp[0] * 0.0625f));
    const int py = __builtin_amdgcn_readfirstlane(__float2int_rn(rp[1] * 0.0625f));
    const int qx = __builtin_amdgcn_readfirstlane(__float2int_rn(rp[2] * 0.0625f));
    const int qy = __builtin_amdgcn_readfirstlane(__float2int_rn(rp[3] * 0.0625f));
    const int roi_w = max(qx - px + 1, 1);
    const int roi_h = max(qy - py + 1, 1);
    const int psw = (roi_w + POOL - 1) / POOL;
    const int psh = (roi_h + POOL - 1) / POOL;
    const int pad_l = (psw * POOL - roi_w) >> 1;
    const int pad_t = (psh * POOL - roi_h) >> 1;

    // quad coverage of [px,qx]; clamped duplicate lanes hit the same lines
    const int qbase = px >> 2;
    const int nq    = (qx >> 2) - qbase + 1;
    const int Lq    = min(lx, nq - 1);
    const int xq    = qbase + Lq;

    const int c = c0 + cs;
    const float4* fp4 = (const float4*)feat + ((size_t)((b << 8) + c) << 10);

    // ---- phase 1 (exact tier ladder on psh; big tiers split into 2 batches) ----
    float4 acc[POOL];
    switch (psh) {
        case 1:  col_max4<1 >(fp4, py, psh, pad_t, roi_h, xq, acc); break;
        case 2:  col_max4<2 >(fp4, py, psh, pad_t, roi_h, xq, acc); break;
        case 3:  col_max4<3 >(fp4, py, psh, pad_t, roi_h, xq, acc); break;
        case 4:  col_max4<4 >(fp4, py, psh, pad_t, roi_h, xq, acc); break;
        case 5:  col_max4<5 >(fp4, py, psh, pad_t, roi_h, xq, acc); break;
        case 6:  col_max4<6 >(fp4, py, psh, pad_t, roi_h, xq, acc); break;
        case 7:
        case 8:  col_max4<8 >(fp4, py, psh, pad_t, roi_h, xq, acc); break;
        default: col_max4<10>(fp4, py, psh, pad_t, roi_h, xq, acc); break;
    }

    // ---- phase 2 setup (active lanes: i7 = channel slot, j7 = pooled col) ----
    __shared__ __attribute__((aligned(16))) float lds[4][2][4][64];
    const bool active = lane < 28;
    const int i7  = lane / 7;
    const int j7  = lane - i7 * 7;
    const int pxl = px & 3;
    const int lox = max(j7 * psw - pad_l, 0);
    const int hix = min((j7 + 1) * psw - pad_l, roi_w) - 1;
    const int xs  = pxl + lox;                 // >= 0
    const int xe  = pxl + hix;                 // <= 63; < xs if empty
    const int xec = max(xe, 0);
    const bool xempty = xe < xs;
    const bool padc = (j7 * psw < pad_l) | ((j7 + 1) * psw > pad_l + roi_w);
    const size_t obase = ((size_t)(br << 8) + c0 + i7) * 49 + j7;
    float* ldsbase = &lds[wv][0][0][0];

    switch (psw) {
        case 1:  phase2_run<1 >(acc, ldsbase, Lq, cs, active, i7, xs, xec, xempty, padc, psh, pad_t, roi_h, out, obase); break;
        case 2:  phase2_run<2 >(acc, ldsbase, Lq, cs, active, i7, xs, xec, xempty, padc, psh, pad_t, roi_h, out, obase); break;
        case 3:  phase2_run<3 >(acc, ldsbase, Lq, cs, active, i7, xs, xec, xempty, padc, psh, pad_t, roi_h, out, obase); break;
        case 4:  phase2_run<4 >(acc, ldsbase, Lq, cs, active, i7, xs, xec, xempty, padc, psh, pad_t, roi_h, out, obase); break;
        case 5:  phase2_run<5 >(acc, ldsbase, Lq, cs, active, i7, xs, xec, xempty, padc, psh, pad_t, roi_h, out, obase); break;
        case 6:  phase2_run<6 >(acc, ldsbase, Lq, cs, active, i7, xs, xec, xempty, padc, psh, pad_t, roi_h, out, obase); break;
        case 7:
        case 8:  phase2_run<8 >(acc, ldsbase, Lq, cs, active, i7, xs, xec, xempty, padc, psh, pad_t, roi_h, out, obase); break;
        default: phase2_run<10>(acc, ldsbase, Lq, cs, active, i7, xs, xec, xempty, padc, psh, pad_t, roi_h, out, obase); break;
    }
}

extern "C" void kernel_launch(void* const* d_in, const int* in_sizes, int n_in,
                              void* d_out, int out_size, void* d_ws, size_t ws_size,
                              hipStream_t stream) {
    const float* feat = (const float*)d_in[0];
    const float* rois = (const float*)d_in[1];
    float* out = (float*)d_out;

    // 2*64 ROIs x 256 channels; 4 channels/wave, 4 waves/block -> 2048 blocks
    const int blocks = 2 * 64 * 256 / 16;
    roi_pool_kernel<<<blocks, 256, 0, stream>>>(feat, rois, out);
}